// Round 2
// baseline (194.960 us; speedup 1.0000x reference)
//
#include <hip/hip_runtime.h>
#include <hip/hip_bf16.h>

#define IN_F   64
#define OUT_F  64
#define N_RELS 32
#define N_BAS  30
#define KROW   2048               // k = i*32 + b  (i feature 0..63, b slot 0..31)
#define B1CHUNK 8192

typedef __attribute__((ext_vector_type(8))) short short8v;
typedef __attribute__((ext_vector_type(8))) _Float16 half8v;
typedef __attribute__((ext_vector_type(4))) float f32x4;

__device__ __forceinline__ int dmin(int a, int b) { return a < b ? a : b; }
__device__ __forceinline__ unsigned short f2bf(float f) {
    __hip_bfloat16 h = __float2bfloat16(f);
    return *(unsigned short*)&h;
}

// ---------- K1: bbT[o][i*32+b] : b<30 -> basis[b][i][o], b==30 -> sw[i][o], b==31 -> (i==0)?bias[o]:0
__global__ void k_bbt(const float* __restrict__ basis, const float* __restrict__ sw,
                      const float* __restrict__ bias, __hip_bfloat16* __restrict__ bbT) {
    int idx = blockIdx.x * blockDim.x + threadIdx.x;
    if (idx >= OUT_F * KROW) return;
    int o = idx >> 11, k = idx & (KROW - 1);
    int i = k >> 5, b = k & 31;
    float v;
    if (b < N_BAS)      v = basis[((size_t)b * IN_F + i) * OUT_F + o];
    else if (b == 30)   v = sw[(size_t)i * OUT_F + o];
    else                v = (i == 0) ? bias[o] : 0.f;
    bbT[idx] = __float2bfloat16(v);
}

// ---------- K2: coarse histogram by tgt>>8 ----------
__global__ void __launch_bounds__(256)
k_b1a(const int* __restrict__ tgt, int* __restrict__ gsum, int E) {
    __shared__ int lh[256];
    int tid = threadIdx.x;
    lh[tid] = 0;
    __syncthreads();
    for (int i = blockIdx.x * blockDim.x + tid; i < E; i += gridDim.x * blockDim.x)
        atomicAdd(&lh[tgt[i] >> 8], 1);
    __syncthreads();
    if (lh[tid]) atomicAdd(&gsum[tid], lh[tid]);
}

// ---------- K3: tiny scan of coarse buckets ----------
__global__ void k_scanB(const int* __restrict__ gsum, int* __restrict__ gexcl,
                        int* __restrict__ bcur, int* __restrict__ off, int NB, int N) {
    int l = threadIdx.x;
    int a0 = (4*l+0 < NB) ? gsum[4*l+0] : 0;
    int a1 = (4*l+1 < NB) ? gsum[4*l+1] : 0;
    int a2 = (4*l+2 < NB) ? gsum[4*l+2] : 0;
    int a3 = (4*l+3 < NB) ? gsum[4*l+3] : 0;
    int s = a0 + a1 + a2 + a3;
    int sc = s;
    for (int d = 1; d < 64; d <<= 1) {
        int o = __shfl_up(sc, d, 64);
        if (l >= d) sc += o;
    }
    int base = sc - s;
    if (4*l+0 < NB) { gexcl[4*l+0] = base;          bcur[4*l+0] = base; }
    if (4*l+1 < NB) { gexcl[4*l+1] = base+a0;       bcur[4*l+1] = base+a0; }
    if (4*l+2 < NB) { gexcl[4*l+2] = base+a0+a1;    bcur[4*l+2] = base+a0+a1; }
    if (4*l+3 < NB) { gexcl[4*l+3] = base+a0+a1+a2; bcur[4*l+3] = base+a0+a1+a2; }
    if (l == 63) { gexcl[NB] = sc; off[N] = sc; }
}

// ---------- K4: coarse bucket scatter ----------
__global__ void __launch_bounds__(1024)
k_b1(const int* __restrict__ src, const int* __restrict__ tgt, const int* __restrict__ et,
     int* __restrict__ bcur, unsigned* __restrict__ ssr, int E) {
    __shared__ unsigned ls_p[B1CHUNK];
    __shared__ unsigned char ls_b[B1CHUNK];
    __shared__ int lh[256], lbase[256], gbase[256], lcur[256];
    int tid = threadIdx.x;
    int e0 = blockIdx.x * B1CHUNK;
    int n = E - e0; if (n > B1CHUNK) n = B1CHUNK;
    if (tid < 256) { lh[tid] = 0; lcur[tid] = 0; }
    __syncthreads();
    unsigned pr[8]; int br[8];
#pragma unroll
    for (int k = 0; k < 8; ++k) {
        int i = k * 1024 + tid;
        br[k] = -1;
        if (i < n) {
            int t = tgt[e0 + i];
            br[k] = t >> 8;
            pr[k] = ((unsigned)(t & 255) << 21) | ((unsigned)src[e0 + i] << 5) | (unsigned)et[e0 + i];
            atomicAdd(&lh[br[k]], 1);
        }
    }
    __syncthreads();
    if (tid < 64) {
        int a0 = lh[4*tid], a1 = lh[4*tid+1], a2 = lh[4*tid+2], a3 = lh[4*tid+3];
        int s = a0 + a1 + a2 + a3, sc = s;
        for (int d = 1; d < 64; d <<= 1) {
            int o = __shfl_up(sc, d, 64);
            if (tid >= d) sc += o;
        }
        int base = sc - s;
        lbase[4*tid] = base; lbase[4*tid+1] = base+a0;
        lbase[4*tid+2] = base+a0+a1; lbase[4*tid+3] = base+a0+a1+a2;
    }
    __syncthreads();
    if (tid < 256 && lh[tid]) gbase[tid] = atomicAdd(&bcur[tid], lh[tid]);
    __syncthreads();
#pragma unroll
    for (int k = 0; k < 8; ++k) {
        if (br[k] >= 0) {
            int pos = atomicAdd(&lcur[br[k]], 1);
            int s = lbase[br[k]] + pos;
            ls_p[s] = pr[k];
            ls_b[s] = (unsigned char)br[k];
        }
    }
    __syncthreads();
#pragma unroll
    for (int k = 0; k < 8; ++k) {
        int i = k * 1024 + tid;
        if (i < n) {
            int b = ls_b[i];
            ssr[gbase[b] + (i - lbase[b])] = ls_p[i];
        }
    }
}

// ---------- K5: per-bucket fine sort ----------
__global__ void __launch_bounds__(256)
k_b2(const unsigned* __restrict__ ssr, const int* __restrict__ gexcl,
     int* __restrict__ off, unsigned* __restrict__ ssr2, int N) {
    __shared__ int lh[256], lofs[256], lcur[256];
    int g = blockIdx.x, tid = threadIdx.x;
    int o0 = gexcl[g], o1 = gexcl[g + 1];
    lh[tid] = 0;
    __syncthreads();
    for (int i = o0 + tid; i < o1; i += 256)
        atomicAdd(&lh[ssr[i] >> 21], 1);
    __syncthreads();
    if (tid < 64) {
        int a0 = lh[4*tid], a1 = lh[4*tid+1], a2 = lh[4*tid+2], a3 = lh[4*tid+3];
        int s = a0 + a1 + a2 + a3, sc = s;
        for (int d = 1; d < 64; d <<= 1) {
            int o = __shfl_up(sc, d, 64);
            if (tid >= d) sc += o;
        }
        int base = sc - s;
        lofs[4*tid] = base; lofs[4*tid+1] = base+a0;
        lofs[4*tid+2] = base+a0+a1; lofs[4*tid+3] = base+a0+a1+a2;
    }
    __syncthreads();
    int t = (g << 8) + tid;
    if (t < N) off[t] = o0 + lofs[tid];
    lcur[tid] = o0 + lofs[tid];
    __syncthreads();
    for (int i = o0 + tid; i < o1; i += 256) {
        unsigned p = ssr[i];
        int pos = atomicAdd(&lcur[p >> 21], 1);
        ssr2[pos] = p;
    }
}

// ---------- K6: fused v5 — edge phase as MFMA GEMM (K=32 edges/tile, fp16 inputs) ----------
// Per target t: Y^T[i][b] = sum_e x[src_e][i] * coeff[r_e][b]  via mfma_f32_16x16x32_f16
//   A (M=64 feats, 4 m-tiles): lane l elem j = x[src_{e_j}][m*16+(l&15)], e_j=(l>>4)*8+j
//   B (N=32 slots, 2 n-tiles): lane l elem j = cofs[r_{e_j}][n*16+(l&15)]  (fp16 LDS, pad row 32 = 0)
//   D: i = m*16+(l>>4)*4+q, b = n*16+(l&15)  ->  zb[w][i*32+b]  (phase 2/3 unchanged)
__global__ void __launch_bounds__(1024, 4)
k_fused(const float* __restrict__ x, const unsigned* __restrict__ ssr2,
        const int* __restrict__ off, const float* __restrict__ coeff,
        const __hip_bfloat16* __restrict__ bbT, float* __restrict__ out, int N) {
    __shared__ __align__(16) unsigned char zb[16 * 4096];   // 16 x 2048 bf16, XOR-swizzled
    __shared__ __align__(16) float pf[16 * 256];            // phase-2 partials; first 2112B alias cofs
    unsigned short* cofs = (unsigned short*)pf;             // [33][32] fp16 (row 32 = zeros)
    int tid = threadIdx.x;
    int w = tid >> 6, lane = tid & 63;
    int t0 = blockIdx.x * 16;
    int t = t0 + w;

    // stage coeff -> fp16 LDS [33][32]; cols 30,31 zero; row 32 zero (pad row for e>=deg)
    for (int idx = tid; idx < 33 * 32; idx += 1024) {
        int r = idx >> 5, b = idx & 31;
        float v = (r < 32 && b < N_BAS) ? coeff[r * N_BAS + b] : 0.f;
        _Float16 h = (_Float16)v;
        cofs[idx] = *(unsigned short*)&h;
    }
    __syncthreads();

    int lane15 = lane & 15;
    int vq = (lane >> 4) << 3;            // edge-slot base of this quadrant
    int vperm = (lane & 48) << 1;         // = (lane>>4)*8*4, bpermute byte base
    unsigned lanef4 = (unsigned)(lane15 << 2);

    float xself = 0.f;
    int deg = 0;
    f32x4 acc[4][2];
    {
        f32x4 z = {0.f, 0.f, 0.f, 0.f};
#pragma unroll
        for (int m = 0; m < 4; ++m) { acc[m][0] = z; acc[m][1] = z; }
    }

    if (t < N) {
        int s0 = __builtin_amdgcn_readfirstlane(off[t]);
        int s1 = __builtin_amdgcn_readfirstlane(off[t + 1]);
        deg = s1 - s0;
        xself = x[((size_t)t << 6) + lane];
        if (deg > 0) {
            const char* xB = (const char*)x;
            int last = s1 - 1;
            for (int kt = 0; kt * 32 < deg; ++kt) {
                int base = s0 + kt * 32;
                // one vector load fetches this tile's 32 edge words (lanes 0..31; 32..63 dup)
                unsigned ew = ssr2[dmin(base + (lane & 31), last)];
                int rem = deg - kt * 32;
                float xr[4][8];
                unsigned short b0u[8], b1u[8];
#pragma unroll
                for (int j = 0; j < 8; ++j) {
                    unsigned wj = (unsigned)__builtin_amdgcn_ds_bpermute(vperm + j * 4, (int)ew);
                    unsigned xoff = (((wj >> 5) & 0xFFFFu) << 8) + lanef4;
                    unsigned rrow = ((vq + j) < rem) ? (wj & 31u) : 32u;  // pad -> zero row
                    const unsigned short* cp = cofs + (rrow << 5) + lane15;
                    b0u[j] = cp[0];
                    b1u[j] = cp[16];
#pragma unroll
                    for (int m = 0; m < 4; ++m)
                        xr[m][j] = *(const float*)(xB + xoff + m * 64);
                }
                union { unsigned short u[8]; half8v h; } bf0, bf1;
#pragma unroll
                for (int j = 0; j < 8; ++j) { bf0.u[j] = b0u[j]; bf1.u[j] = b1u[j]; }
#pragma unroll
                for (int m = 0; m < 4; ++m) {
                    union { _Float16 f[8]; half8v h; } af;
#pragma unroll
                    for (int j = 0; j < 8; ++j) af.f[j] = (_Float16)xr[m][j];
                    acc[m][0] = __builtin_amdgcn_mfma_f32_16x16x32_f16(af.h, bf0.h, acc[m][0], 0, 0, 0);
                    acc[m][1] = __builtin_amdgcn_mfma_f32_16x16x32_f16(af.h, bf1.h, acc[m][1], 0, 0, 0);
                }
            }
        }
    }

    // ---- epilogue: Y * inv-deg -> zb row w (bf16, k = i*32+b, XOR-swizzled) ----
    {
        float inv = 1.f / fmaxf((float)deg, 1.f);
        unsigned rb = (unsigned)w << 12;
        unsigned swz = (unsigned)((w & 7) << 4);
#pragma unroll
        for (int m = 0; m < 4; ++m)
#pragma unroll
            for (int n = 0; n < 2; ++n)
#pragma unroll
                for (int q = 0; q < 4; ++q) {
                    int i = (m << 4) + ((lane >> 4) << 2) + q;
                    int b = (n << 4) + lane15;
                    unsigned byt = ((unsigned)(i << 6) + (unsigned)(b << 1)) ^ swz;
                    *(unsigned short*)(zb + rb + byt) = f2bf(acc[m][n][q] * inv);
                }
        // slot b=30: xself (lane=feature i); slot b=31: 1.0 at i=0 (rest already zeroed above)
        unsigned byt = (((unsigned)lane << 6) + 60u) ^ swz;
        *(unsigned short*)(zb + rb + byt) = f2bf(xself);
        if (lane == 0)
            *(unsigned short*)(zb + rb + (62u ^ swz)) = (unsigned short)0x3F80;
    }
    __syncthreads();

    // ---- MFMA phase 2 (unchanged): wave w -> colblk=w&3, K-quarter kq=w>>2 (512 each, 16 steps)
    int l15 = lane & 15, lk = lane >> 4;
    int colblk = w & 3, kq = w >> 2;
    const short8v* bp = (const short8v*)(bbT + (((size_t)(colblk * 16 + l15)) << 11) + (kq << 9) + lk * 8);
    unsigned arow = (unsigned)l15 << 12;
    unsigned aswz = (unsigned)((l15 & 7) << 4);
    f32x4 acc2 = {0.f, 0.f, 0.f, 0.f};
#pragma unroll 4
    for (int s = 0; s < 16; ++s) {
        unsigned abyte = ((unsigned)((kq << 10) + (s << 6) + (lk << 4))) ^ aswz;
        short8v a = *(const short8v*)(zb + arow + abyte);
        short8v b = bp[s * 4];
        acc2 = __builtin_amdgcn_mfma_f32_16x16x32_bf16(a, b, acc2, 0, 0, 0);
    }
#pragma unroll
    for (int q = 0; q < 4; ++q)                      // D: col=lane&15, row=lk*4+q
        pf[(w << 8) + ((lk << 2) + q) * 16 + l15] = acc2[q];
    __syncthreads();

    // ---- reduce 4 K-quarters + write (1024 threads = 1024 outputs)
    {
        int row = w, col = lane;
        int cb = col >> 4, cl = col & 15;
        int tt = t0 + row;
        if (tt < N) {
            float v = pf[((0 << 2) + cb) * 256 + row * 16 + cl]
                    + pf[((1 << 2) + cb) * 256 + row * 16 + cl]
                    + pf[((2 << 2) + cb) * 256 + row * 16 + cl]
                    + pf[((3 << 2) + cb) * 256 + row * 16 + cl];
            out[((size_t)tt << 6) + col] = v;
        }
    }
}

extern "C" void kernel_launch(void* const* d_in, const int* in_sizes, int n_in,
                              void* d_out, int out_size, void* d_ws, size_t ws_size,
                              hipStream_t stream) {
    const float* x     = (const float*)d_in[0];
    const int*   eidx  = (const int*)d_in[1];   // (2, E)
    const int*   etype = (const int*)d_in[2];
    const float* basis = (const float*)d_in[4];
    const float* coeff = (const float*)d_in[5];
    const float* sw    = (const float*)d_in[6];
    const float* bias  = (const float*)d_in[7];

    const int E = in_sizes[1] / 2;
    const int N = out_size / OUT_F;
    const int NB = (N + 255) >> 8;
    const int* srcv = eidx;
    const int* tgtv = eidx + E;
    float* out = (float*)d_out;

    size_t p = 0;
    auto alloc = [&](size_t bytes) { size_t cur = p; p += (bytes + 255) & ~(size_t)255; return cur; };
    char* base = (char*)d_ws;
    __hip_bfloat16* bbT   = (__hip_bfloat16*)(base + alloc((size_t)OUT_F * KROW * 2));
    int*            gsum  = (int*)(base + alloc(256 * 4));
    int*            gexcl = (int*)(base + alloc((size_t)(NB + 1) * 4));
    int*            bcur  = (int*)(base + alloc((size_t)NB * 4));
    int*            off   = (int*)(base + alloc((size_t)(N + 1) * 4));
    unsigned*       ssr   = (unsigned*)(base + alloc((size_t)E * 4));
    unsigned*       ssr2  = (unsigned*)(base + alloc((size_t)E * 4));
    (void)ws_size;

    hipMemsetAsync(gsum, 0, 256 * 4, stream);

    k_bbt<<<(OUT_F * KROW + 255) / 256, 256, 0, stream>>>(basis, sw, bias, bbT);
    k_b1a<<<256, 256, 0, stream>>>(tgtv, gsum, E);
    k_scanB<<<1, 64, 0, stream>>>(gsum, gexcl, bcur, off, NB, N);
    k_b1<<<(E + B1CHUNK - 1) / B1CHUNK, 1024, 0, stream>>>(srcv, tgtv, etype, bcur, ssr, E);
    k_b2<<<NB, 256, 0, stream>>>(ssr, gexcl, off, ssr2, N);
    k_fused<<<(N + 15) / 16, 1024, 0, stream>>>(x, ssr2, off, coeff, bbT, out, N);
}